// Round 5
// baseline (235.336 us; speedup 1.0000x reference)
//
#include <hip/hip_runtime.h>

// out[b, c, f] = x[b, f*WINSTEP + c]   (W is identity framing kernel)
// B=32, T=480000, WINLEN=400, WINSTEP=160, F=2998.

constexpr int WINLEN  = 400;
constexpr int WINSTEP = 160;
constexpr int T_LEN   = 480000;
constexpr int NFRAMES = (T_LEN - WINLEN) / WINSTEP + 1;   // 2998
constexpr int BATCH   = 32;

constexpr int F_TILE  = 64;                                // frames per block
constexpr int CHUNK   = (F_TILE - 1) * WINSTEP + WINLEN;   // 10480 floats staged
// swizzle map(t) = t + t/WINSTEP  -> phase-2 lane stride becomes 161 words (bank-free)
constexpr int LDS_N   = CHUNK + CHUNK / WINSTEP + 1;       // 10546 floats = 42.2 KB

__global__ __launch_bounds__(256) void frames_kernel(
    const float* __restrict__ x, float* __restrict__ out)
{
    __shared__ float sm[LDS_N];
    const int tile = blockIdx.x;           // 0..46
    const int b    = blockIdx.y;           // 0..31
    const int f0   = tile * F_TILE;
    const int t0   = f0 * WINSTEP;
    const float* __restrict__ xb = x + (size_t)b * T_LEN;
    const int tid = threadIdx.x;

    // ---- Phase 1: stage input window into LDS (coalesced float4), swizzled.
    // base is a multiple of 4 and 160 % 4 == 0, so a float4 never crosses a
    // 160-word boundary -> swizzled destination stays contiguous.
    for (int base = tid * 4; base < CHUNK; base += 256 * 4) {
        const int tg = t0 + base;
        if (tg < T_LEN) {                   // tg,T both mult. of 4 -> full vec in-bounds
            const float4 v = *reinterpret_cast<const float4*>(xb + tg);
            const int a = base + base / WINSTEP;
            sm[a]     = v.x;
            sm[a + 1] = v.y;
            sm[a + 2] = v.z;
            sm[a + 3] = v.w;
        }
    }
    __syncthreads();

    // ---- Phase 2: each lane owns 2 consecutive frames, loops over channels.
    // Wave: 32 lanes x 2 c-groups -> per c, 32 lanes write 256 B contiguous.
    // LDS read addr = c + c/160 + (fl+k)*161 -> lane bank stride 2 with two
    // c-groups interleaved on odd banks: 32 banks x 2 lanes = conflict-free.
    const int jj = tid & 31;               // frame-pair index in tile
    const int cg = tid >> 5;               // 0..7
    const int fl = 2 * jj;                 // local frame
    const int f  = f0 + fl;
    float* __restrict__ ob = out + (size_t)b * WINLEN * NFRAMES + f;

    const bool full = (f + 1 < NFRAMES);
    const bool one  = (f < NFRAMES);

    #pragma unroll 5
    for (int i = 0; i < WINLEN / 8; ++i) { // 50 iterations
        const int c = cg + 8 * i;
        const int a = c + c / WINSTEP + fl * (WINSTEP + 1);
        const float v0 = sm[a];
        const float v1 = sm[a + (WINSTEP + 1)];
        float* p = ob + (size_t)c * NFRAMES;
        if (full) {
            *reinterpret_cast<float2*>(p) = make_float2(v0, v1);  // 8B aligned: f,c*2998 even
        } else if (one) {
            *p = v0;
        }
    }
}

extern "C" void kernel_launch(void* const* d_in, const int* in_sizes, int n_in,
                              void* d_out, int out_size, void* d_ws, size_t ws_size,
                              hipStream_t stream) {
    const float* x = (const float*)d_in[0];     // (32, 1, 480000) f32
    // d_in[1] = W (identity, unused), d_in[2] = winstep (==160, baked in)
    float* out = (float*)d_out;                 // (32, 400, 2998) f32
    dim3 grid((NFRAMES + F_TILE - 1) / F_TILE, BATCH);
    frames_kernel<<<grid, 256, 0, stream>>>(x, out);
}

// Round 10
// 209.026 us; speedup vs baseline: 1.1259x; 1.1259x over previous
//
#include <hip/hip_runtime.h>

// out[b, c, f] = x[b, f*WINSTEP + c]   (W is identity framing kernel)
// B=32, T=480000, WINLEN=400, WINSTEP=160, F=2998.
// Measured r5: passes bit-exact; dur_us 235.3 of which ~215 us is harness
// d_out/d_ws re-poison fills (2 x 107 us visible in counters); kernel ~20 us.

constexpr int WINLEN  = 400;
constexpr int WINSTEP = 160;
constexpr int T_LEN   = 480000;
constexpr int NFRAMES = (T_LEN - WINLEN) / WINSTEP + 1;   // 2998
constexpr int BATCH   = 32;

constexpr int F_TILE  = 64;                                // frames per block
constexpr int NTILES  = (NFRAMES + F_TILE - 1) / F_TILE;   // 47
constexpr int NWG     = NTILES * BATCH;                    // 1504 (mult of 8)
constexpr int CHUNK   = (F_TILE - 1) * WINSTEP + WINLEN;   // 10480 floats staged
// swizzle map(t) = t + t/WINSTEP  -> phase-2 lane stride becomes 161 words (bank-free)
constexpr int LDS_N   = CHUNK + CHUNK / WINSTEP + 1;       // 10546 floats = 42.2 KB

__global__ __launch_bounds__(256) void frames_kernel(
    const float* __restrict__ x, float* __restrict__ out)
{
    __shared__ float sm[LDS_N];
    // XCD-aware bijective swizzle (NWG % 8 == 0): XCD k owns all 47 tiles of
    // batches 4k..4k+3 -> inter-tile input overlap (240 floats) and shared
    // partial output cache lines (stride 2998*4 % 64 = 24) stay in one L2.
    const int wgid  = blockIdx.x;
    const int newid = (wgid & 7) * (NWG / 8) + (wgid >> 3);
    const int b     = newid / NTILES;
    const int tile  = newid % NTILES;

    const int f0   = tile * F_TILE;
    const int t0   = f0 * WINSTEP;
    const float* __restrict__ xb = x + (size_t)b * T_LEN;
    const int tid = threadIdx.x;

    // ---- Phase 1: stage input window into LDS (coalesced float4), swizzled.
    // base is a multiple of 4 and 160 % 4 == 0, so a float4 never crosses a
    // 160-word boundary -> swizzled destination stays contiguous.
    for (int base = tid * 4; base < CHUNK; base += 256 * 4) {
        const int tg = t0 + base;
        if (tg < T_LEN) {                   // tg,T both mult. of 4 -> full vec in-bounds
            const float4 v = *reinterpret_cast<const float4*>(xb + tg);
            const int a = base + base / WINSTEP;
            sm[a]     = v.x;
            sm[a + 1] = v.y;
            sm[a + 2] = v.z;
            sm[a + 3] = v.w;
        }
    }
    __syncthreads();

    // ---- Phase 2: each lane owns 2 consecutive frames, loops over channels.
    // Wave: 32 lanes x 2 c-groups -> per c, 32 lanes write 256 B contiguous.
    // LDS read addr = c + c/160 + (fl+k)*161 -> lane bank stride 2 with two
    // c-groups interleaved on odd banks: 32 banks x 2 lanes = conflict-free.
    const int jj = tid & 31;               // frame-pair index in tile
    const int cg = tid >> 5;               // 0..7
    const int fl = 2 * jj;                 // local frame
    const int f  = f0 + fl;
    float* __restrict__ ob = out + (size_t)b * WINLEN * NFRAMES + f;

    const bool full = (f + 1 < NFRAMES);
    const bool one  = (f < NFRAMES);

    #pragma unroll 5
    for (int i = 0; i < WINLEN / 8; ++i) { // 50 iterations
        const int c = cg + 8 * i;
        const int a = c + c / WINSTEP + fl * (WINSTEP + 1);
        const float v0 = sm[a];
        const float v1 = sm[a + (WINSTEP + 1)];
        float* p = ob + (size_t)c * NFRAMES;
        if (full) {
            *reinterpret_cast<float2*>(p) = make_float2(v0, v1);  // 8B aligned: f,c*2998 even
        } else if (one) {
            *p = v0;
        }
    }
}

extern "C" void kernel_launch(void* const* d_in, const int* in_sizes, int n_in,
                              void* d_out, int out_size, void* d_ws, size_t ws_size,
                              hipStream_t stream) {
    const float* x = (const float*)d_in[0];     // (32, 1, 480000) f32
    // d_in[1] = W (identity, unused), d_in[2] = winstep (==160, baked in)
    float* out = (float*)d_out;                 // (32, 400, 2998) f32
    frames_kernel<<<dim3(NWG), 256, 0, stream>>>(x, out);
}